// Round 9
// baseline (433.322 us; speedup 1.0000x reference)
//
#include <hip/hip_runtime.h>
#include <math.h>

// Full-fidelity emulation of the reference as run by jax-rocm EAGERLY on this
// GPU (x64 on): all f64 transcendentals are __ocml_*_f64 == this kernel's
// exp()/log(). Both stages are inexact because jax lowers exp2(z) ->
// exp(RN(z*RN(ln2))) -- reproduced bit-for-bit.
//
// R9 change (SINGLE VARIABLE vs R8): nontemporal flags removed from ALL
// loads and stores. NT entered in R3 bundled with two wins and was never
// isolated; both known-good BW references on this chip use NORMAL accesses
// (harness fills 6.5 TB/s normal stores; m13 copy 6.29 TB/s normal both),
// while we sit at 4.25 TB/s. Mechanism: NT's no-allocate/streaming policy
// bypasses L2's request coalescing + write combining on the HBM path. R0
// (normal everything) showed ideal FETCH/WRITE (233/280 MB), so the normal
// policy costs no extra traffic despite the 512MB working set > L3.
// Everything else is R8 verbatim:
//  * Persistent resident grid: 1024 blocks x 256 thr; tables built once per
//    block; grid-stride over 256-value tiles; no steady-state barriers.
//  * Iteration-boundary pipelining: pack(cur) -> sched_barrier -> issue
//    loads(next, same buffer, WAR-safe) -> f64 chain(cur) -> store(cur).
//  * Wave-local dataflow: value->lane map v = vwave + (lane&7)*8 +
//    (lane>>3); pack keeps own word (select i==lane&7); store word via one
//    __shfl from lane (lane&56)+i. No LDS data path.
//  * Encode shortcuts (absmax==0 six rounds):
//    - mantissa!=0 -> floor(log(a)/LN2) == E exactly (emu err ~1e-13 vs
//      1.7e-7 distance to integer); subnormal -> clip == -126; mantissa==0
//      (exact pow2) -> rare verbatim ocml log() path.
//    - mant = M + e, |e| <~ 1e-8: for sc > ctz(M), floor(mant*Lm[sc]) ==
//      M>>sc exactly -> parity is bit sc of M; only sc <= ctz(M) (incl. the
//      pow2 M=0 "W-1 garbage" case) runs the original f64 mul+floor step.

#define LN2C 0x1.62e42fefa39efp-1  // RN(ln2), XLA's folded log(2)

typedef unsigned int u32x4 __attribute__((ext_vector_type(4)));

__global__ __launch_bounds__(256) void spike_gelu_kernel(
    const u32x4* __restrict__ in, u32x4* __restrict__ out,
    int n_vals, int n_tiles) {
#pragma clang fp contract(off)
  const double LN2 = LN2C;
  // Tables (exact ocml-call replicas of the reference's constant arrays):
  __shared__ double Wdec[8];     // decode exponent weights exp2emu(7..0)
  __shared__ double Lms[23];     // ladder scales exp2emu(0..-22)
  __shared__ double E1t[256];    // ordered Wdec sum -> exp((e_c-127)*LN2)
  __shared__ double Vdec[23];    // decode fraction weights exp2emu(-1..-23)
  __shared__ double P2t[254];    // encode exp(-e0*LN2), e0 in [-126,127]
  __shared__ uint32_t etab[256]; // 8-step exponent floor-ladder per eb

  const int tid = threadIdx.x;
  const int lane = tid & 63;
  const int wid = tid >> 6;  // 0..3
  const int n_chunks = n_vals * 8;
  const int tstep = gridDim.x;  // grid-stride over 256-value tiles

  int tile = blockIdx.x;

  // ---- prologue: issue tile-0 loads (in flight under the table build) -----
  u32x4 A[8];
  {
    const int cb = tile * 2048 + wid * 512 + lane;
#pragma unroll
    for (int i = 0; i < 8; ++i) {
      int g = cb + i * 64;
      u32x4 b = {0u, 0u, 0u, 0u};
      if (g < n_chunks) b = in[g];
      A[i] = b;
    }
  }

  // ---- table stage 1 ------------------------------------------------------
  if (tid < 8) Wdec[tid] = exp((double)(7 - tid) * LN2);
  if (tid >= 31 && tid < 54) Lms[tid - 31] = exp((double)(31 - tid) * LN2);
  __syncthreads();
  // ---- table stage 2 (reference op order) ---------------------------------
  if (tid == 0) {
    E1t[0] = exp(-126.0 * LN2);  // subnormal-branch scale (e_c==0)
  } else {
    double e_c = 0.0;
#pragma unroll
    for (int j = 0; j < 8; ++j)   // ascending-j einsum accumulation, verbatim
      if ((tid >> (7 - j)) & 1) e_c = e_c + Wdec[j];
    E1t[tid] = exp((e_c - 127.0) * LN2);
  }
  if (tid < 23) Vdec[tid] = exp((double)(-1 - tid) * LN2);
  if (tid < 254) P2t[tid] = exp((double)(126 - tid) * LN2);  // exp(-e0*LN2)
  if (tid >= 1 && tid < 255) {  // exponent-bit ladder, original formula
    double eb = (double)tid;
    uint32_t r = 0;
#pragma unroll
    for (int sc = 7; sc >= 0; --sc) {
      double f = floor(eb * Lms[sc]);
      double md = f - 2.0 * floor(0.5 * f);
      r |= ((uint32_t)md) << (23 + sc);
    }
    etab[tid] = r;
  } else {
    etab[tid] = 0u;  // hygiene, never read
  }
  __syncthreads();  // tables ready; no further block-wide coupling

  const int nibshift = 28 - 4 * (lane & 7);
  const int keep = lane & 7;

  // ---- steady-state resident loop (no barriers, no mid-chain memory) ------
  for (;;) {
    // pack(cur): wave-local bit transpose. Chunk cb+i*64 holds value
    // vwave+i*8+(lane>>3), nibble pos lane&7; after the 3 xor-ors lane keeps
    // its own value's word (v = vwave + (lane&7)*8 + (lane>>3)) at i==lane&7.
    uint32_t w0 = 0u;
#pragma unroll
    for (int i = 0; i < 8; ++i) {
      u32x4 b = A[i];
      uint32_t p = (((((b.x >> 23) & 1u) << 3) | (((b.y >> 23) & 1u) << 2) |
                     (((b.z >> 23) & 1u) << 1) | ((b.w >> 23) & 1u)))
                   << nibshift;
      p |= __shfl_xor(p, 1);
      p |= __shfl_xor(p, 2);
      p |= __shfl_xor(p, 4);
      if (keep == i) w0 = p;
    }
    // keep the compiler from hoisting next-tile loads above the pack (would
    // force a second 32-VGPR buffer and cross the 128-VGPR cliff)
    __builtin_amdgcn_sched_barrier(0);

    // issue loads(next) into the SAME buffer: WAR-safe (pack's reads issued
    // above); they have the entire f64 chain + store below to land.
    const int ntile = tile + tstep;
    const bool havenext = ntile < n_tiles;
    if (havenext) {
      const int cb = ntile * 2048 + wid * 512 + lane;
#pragma unroll
      for (int i = 0; i < 8; ++i) {
        int g = cb + i * 64;
        u32x4 b = {0u, 0u, 0u, 0u};
        if (g < n_chunks) b = in[g];
        A[i] = b;
      }
    }

    // ---- per-value chain (bit-identical to R4/R6/R8) ----------------------
    const int vwave = tile * 256 + wid * 64;
    const int v0 = vwave + (lane & 7) * 8 + (lane >> 3);
    const bool ok0 = v0 < n_vals;

    // DECODE
    double f0 = 0.0;
#pragma unroll
    for (int j = 0; j < 23; ++j)
      if ((w0 >> (22 - j)) & 1u) f0 = f0 + Vdec[j];
    uint32_t ei0 = (w0 >> 23) & 0xFFu;
    double sg0 = (w0 >> 31) ? -1.0 : 1.0;
    double fa0 = ei0 ? (1.0 + f0) : f0;
    double x0 = (sg0 * E1t[ei0]) * fa0;

    // f64 GELU, exp-form logistic, ocml exp
    double t0 = 1.702 * x0;
    double e0v = exp(-t0);
    double s0 = 1.0 / (1.0 + e0v);
    double y0 = x0 * s0;
    float yf0 = (float)y0;   // astype(float32): RN
    double yd0 = (double)yf0;

    // ENCODE
    double a0 = fabs(yd0);
    uint32_t yb0 = __float_as_uint(yf0);
    uint32_t Ef0 = (yb0 >> 23) & 0xFFu;
    uint32_t mbf0 = yb0 & 0x7FFFFFu;
    int e00 = (Ef0 == 0u) ? -126 : (int)Ef0 - 127;
    bool pw0 = ok0 && (a0 > 0.0) && (Ef0 != 0u) && (mbf0 == 0u);
    if (__builtin_expect(pw0, 0)) {  // exact pow2: ocml log boundary, verbatim
      double e0 = floor(log(a0) / LN2);
      e00 = (int)fmin(fmax(e0, -126.0), 127.0);
    }
    double p20 = P2t[e00 + 126];
    double m10 = a0 * p20;               // RN: may be W' +- eps
    double mant0 = (m10 - 1.0) * 8388608.0;  // Sterbenz-exact, exact scale
    int M0 = (int)rint(mant0);
    uint32_t mb0 = ((uint32_t)M0) & 0x7FFFFFu;
    int T0 = M0 ? __builtin_ctz((uint32_t)M0) : 23;
    int L0 = T0 < 22 ? T0 : 22;
    for (int sc = 0; sc <= L0; ++sc) {   // boundary scs: original f64 math
      double f = floor(mant0 * Lms[sc]);
      mb0 = (mb0 & ~(1u << sc)) | (((uint32_t)(((int)f) & 1)) << sc);
    }
    uint32_t ob0 = (yb0 & 0x80000000u) | etab[e00 + 127] | mb0;
    ob0 = (ok0 && a0 > 0.0) ? ob0 : 0u;

    // ---- store(cur): wave-local pulse expansion, normal stores ------------
    // Chunk cb+i*64 needs value vwave+i*8+(lane>>3), held at lane (lane&56)+i.
    uint32_t wv[8];
#pragma unroll
    for (int i = 0; i < 8; ++i) wv[i] = __shfl(ob0, (lane & 56) + i);
    const int cb = tile * 2048 + wid * 512 + lane;
    const int base = 31 - 4 * (lane & 7);
#pragma unroll
    for (int i = 0; i < 8; ++i) {
      int g = cb + i * 64;
      if (g < n_chunks) {
        uint32_t wa = wv[i];
        u32x4 o;
        o.x = ((wa >> base) & 1u) * 0x3F800000u;
        o.y = ((wa >> (base - 1)) & 1u) * 0x3F800000u;
        o.z = ((wa >> (base - 2)) & 1u) * 0x3F800000u;
        o.w = ((wa >> (base - 3)) & 1u) * 0x3F800000u;
        out[g] = o;
      }
    }

    if (!havenext) break;
    tile = ntile;
  }
}

extern "C" void kernel_launch(void* const* d_in, const int* in_sizes, int n_in,
                              void* d_out, int out_size, void* d_ws, size_t ws_size,
                              hipStream_t stream) {
  int n_vals = in_sizes[0] / 32;
  int n_tiles = (n_vals + 255) / 256;
  int grid = n_tiles < 1024 ? n_tiles : 1024;
  spike_gelu_kernel<<<grid, 256, 0, stream>>>(
      (const u32x4*)d_in[0], (u32x4*)d_out, n_vals, n_tiles);
}

// Round 12
// 419.306 us; speedup vs baseline: 1.0334x; 1.0334x over previous
//
#include <hip/hip_runtime.h>
#include <math.h>

// Full-fidelity emulation of the reference as run by jax-rocm EAGERLY on this
// GPU (x64 on): all f64 transcendentals are __ocml_*_f64 == this kernel's
// exp()/log(). Both stages are inexact because jax lowers exp2(z) ->
// exp(RN(z*RN(ln2))) -- reproduced bit-for-bit.
//
// R12 == R10 resubmitted (R10/R11 benches were infrastructure failures --
// container acquire failed; audit found no kernel-side hang/fault mechanism:
// loop strictly advances, all accesses bounds-guarded, no in-loop barriers).
//
// R10 changes (bit movement only -- w0 / stored bits identical to R8 by
// construction; f64 chain verbatim):
//  * R9 post-mortem: removing NT cost +15.1us -> NT restored everywhere
//    (R8 config, best measured 418.2).
//  * Pack: per-chunk 3-shfl OR-reduce (24 DS ops + ~112 VALU per value)
//    replaced by local nibble accumulation X |= nib<<4i (no cross-lane),
//    then ONE 3-round shfl_xor butterfly that transposes the 8x8 nibble
//    matrix of each 8-lane group (3 DS + ~20 VALU), then nibble-reverse.
//    Proof: round d swaps elements (p,k)<->(p^d,k^d) where (p&d)!=(k&d);
//    composing d=1,2,4 gives new[p][k]=old[k][p] (full transpose). After
//    transpose lane p's slot k = nib_k(value p*8+g); value word needs nib_q
//    at bits 28-4q = slot 7-q -> nibble-reverse. Same value->lane map as R8.
//  * Store: 8 bpermutes + ~80 VALU expansion replaced by nibble-reverse +
//    same butterfly (Z slot i = this lane's nibble of value i*8+g) + per
//    chunk 1 nibble extract + 16-entry LDS LUT (ds_read_b128) expanding
//    4 bits -> 16B of pulses.
//  * Everything else R8 verbatim: persistent 1024x256 grid, per-block
//    tables, grid-stride tiles, pack -> sched_barrier -> next-tile NT loads
//    (same buffer, WAR-safe) -> f64 chain -> NT stores; no loop barriers.
//  * Encode shortcuts unchanged (absmax==0 seven rounds):
//    - mantissa!=0 -> floor(log(a)/LN2) == E exactly; subnormal -> clip ==
//      -126; mantissa==0 (exact pow2) -> rare verbatim ocml log() path.
//    - mant = M + e, |e| <~ 1e-8: for sc > ctz(M), floor(mant*Lm[sc]) ==
//      M>>sc exactly -> parity is bit sc of M; only sc <= ctz(M) (incl. the
//      pow2 M=0 "W-1 garbage" case) runs the original f64 mul+floor step.

#define LN2C 0x1.62e42fefa39efp-1  // RN(ln2), XLA's folded log(2)

typedef unsigned int u32x4 __attribute__((ext_vector_type(4)));

__device__ __forceinline__ uint32_t nib_transpose8(uint32_t x, int p) {
  // Transpose the 8x8 nibble matrix held across the 8 lanes of a group
  // (row = lane p, col = nibble slot k). Involution; also its own inverse.
  uint32_t r;
  r = __shfl_xor(x, 1);
  x = (p & 1) ? ((x & 0xF0F0F0F0u) | ((r >> 4) & 0x0F0F0F0Fu))
              : ((x & 0x0F0F0F0Fu) | ((r << 4) & 0xF0F0F0F0u));
  r = __shfl_xor(x, 2);
  x = (p & 2) ? ((x & 0xFF00FF00u) | ((r >> 8) & 0x00FF00FFu))
              : ((x & 0x00FF00FFu) | ((r << 8) & 0xFF00FF00u));
  r = __shfl_xor(x, 4);
  x = (p & 4) ? ((x & 0xFFFF0000u) | ((r >> 16) & 0x0000FFFFu))
              : ((x & 0x0000FFFFu) | ((r << 16) & 0xFFFF0000u));
  return x;
}

__device__ __forceinline__ uint32_t nib_reverse(uint32_t x) {
  // Reverse the 8 nibbles of x (slot k <-> slot 7-k).
  uint32_t b = __builtin_bswap32(x);
  return ((b >> 4) & 0x0F0F0F0Fu) | ((b << 4) & 0xF0F0F0F0u);
}

__global__ __launch_bounds__(256) void spike_gelu_kernel(
    const u32x4* __restrict__ in, u32x4* __restrict__ out,
    int n_vals, int n_tiles) {
#pragma clang fp contract(off)
  const double LN2 = LN2C;
  // Tables (exact ocml-call replicas of the reference's constant arrays):
  __shared__ double Wdec[8];     // decode exponent weights exp2emu(7..0)
  __shared__ double Lms[23];     // ladder scales exp2emu(0..-22)
  __shared__ double E1t[256];    // ordered Wdec sum -> exp((e_c-127)*LN2)
  __shared__ double Vdec[23];    // decode fraction weights exp2emu(-1..-23)
  __shared__ double P2t[254];    // encode exp(-e0*LN2), e0 in [-126,127]
  __shared__ uint32_t etab[256]; // 8-step exponent floor-ladder per eb
  __shared__ u32x4 lut16[16];    // nibble -> 4 pulse floats (x=bit3..w=bit0)

  const int tid = threadIdx.x;
  const int lane = tid & 63;
  const int kp = lane & 7;   // position within 8-lane group
  const int wid = tid >> 6;  // 0..3
  const int n_chunks = n_vals * 8;
  const int tstep = gridDim.x;  // grid-stride over 256-value tiles

  int tile = blockIdx.x;

  // ---- prologue: issue tile-0 loads (in flight under the table build) -----
  u32x4 A[8];
  {
    const int cb = tile * 2048 + wid * 512 + lane;
#pragma unroll
    for (int i = 0; i < 8; ++i) {
      int g = cb + i * 64;
      u32x4 b = {0u, 0u, 0u, 0u};
      if (g < n_chunks) b = __builtin_nontemporal_load(&in[g]);
      A[i] = b;
    }
  }

  // ---- table stage 1 ------------------------------------------------------
  if (tid < 8) Wdec[tid] = exp((double)(7 - tid) * LN2);
  if (tid >= 31 && tid < 54) Lms[tid - 31] = exp((double)(31 - tid) * LN2);
  __syncthreads();
  // ---- table stage 2 (reference op order) ---------------------------------
  if (tid == 0) {
    E1t[0] = exp(-126.0 * LN2);  // subnormal-branch scale (e_c==0)
  } else {
    double e_c = 0.0;
#pragma unroll
    for (int j = 0; j < 8; ++j)   // ascending-j einsum accumulation, verbatim
      if ((tid >> (7 - j)) & 1) e_c = e_c + Wdec[j];
    E1t[tid] = exp((e_c - 127.0) * LN2);
  }
  if (tid < 23) Vdec[tid] = exp((double)(-1 - tid) * LN2);
  if (tid < 254) P2t[tid] = exp((double)(126 - tid) * LN2);  // exp(-e0*LN2)
  if (tid < 16) {
    u32x4 e;
    e.x = ((tid >> 3) & 1u) * 0x3F800000u;
    e.y = ((tid >> 2) & 1u) * 0x3F800000u;
    e.z = ((tid >> 1) & 1u) * 0x3F800000u;
    e.w = (tid & 1u) * 0x3F800000u;
    lut16[tid] = e;
  }
  if (tid >= 1 && tid < 255) {  // exponent-bit ladder, original formula
    double eb = (double)tid;
    uint32_t r = 0;
#pragma unroll
    for (int sc = 7; sc >= 0; --sc) {
      double f = floor(eb * Lms[sc]);
      double md = f - 2.0 * floor(0.5 * f);
      r |= ((uint32_t)md) << (23 + sc);
    }
    etab[tid] = r;
  } else if (tid == 255 || tid == 0) {
    etab[tid] = 0u;  // hygiene, never read
  }
  __syncthreads();  // tables ready; no further block-wide coupling

  // ---- steady-state resident loop (no barriers, no mid-chain memory) ------
  for (;;) {
    // pack(cur): lane-local nibble accumulation. Chunk cb+i*64 holds value
    // vwave+i*8+(lane>>3); this lane's 4 floats are bits [31-4kp : 28-4kp]
    // of that value. Accumulate nib(iter i) into slot i of X.
    uint32_t X = 0u;
#pragma unroll
    for (int i = 0; i < 8; ++i) {
      u32x4 b = A[i];
      uint32_t nib = (((b.x >> 23) & 1u) << 3) | (((b.y >> 23) & 1u) << 2) |
                     (((b.z >> 23) & 1u) << 1) | ((b.w >> 23) & 1u);
      X |= nib << (4 * i);
    }
    // keep the compiler from hoisting next-tile loads above the A reads
    // (would force a second 32-VGPR buffer and cross the 128-VGPR cliff)
    __builtin_amdgcn_sched_barrier(0);

    // issue loads(next) into the SAME buffer: WAR-safe (A reads issued
    // above); they have the butterfly + f64 chain + store below to land.
    const int ntile = tile + tstep;
    const bool havenext = ntile < n_tiles;
    if (havenext) {
      const int cb = ntile * 2048 + wid * 512 + lane;
#pragma unroll
      for (int i = 0; i < 8; ++i) {
        int g = cb + i * 64;
        u32x4 b = {0u, 0u, 0u, 0u};
        if (g < n_chunks) b = __builtin_nontemporal_load(&in[g]);
        A[i] = b;
      }
    }

    // butterfly: lane kp slot k becomes nib_k(value kp*8+g); nibble-reverse
    // puts nib_q at bits 28-4q -> exactly R8's w0 for v0.
    uint32_t w0 = nib_reverse(nib_transpose8(X, kp));

    // ---- per-value chain (bit-identical to R4/R6/R8) ----------------------
    const int vwave = tile * 256 + wid * 64;
    const int v0 = vwave + kp * 8 + (lane >> 3);
    const bool ok0 = v0 < n_vals;

    // DECODE
    double f0 = 0.0;
#pragma unroll
    for (int j = 0; j < 23; ++j)
      if ((w0 >> (22 - j)) & 1u) f0 = f0 + Vdec[j];
    uint32_t ei0 = (w0 >> 23) & 0xFFu;
    double sg0 = (w0 >> 31) ? -1.0 : 1.0;
    double fa0 = ei0 ? (1.0 + f0) : f0;
    double x0 = (sg0 * E1t[ei0]) * fa0;

    // f64 GELU, exp-form logistic, ocml exp
    double t0 = 1.702 * x0;
    double e0v = exp(-t0);
    double s0 = 1.0 / (1.0 + e0v);
    double y0 = x0 * s0;
    float yf0 = (float)y0;   // astype(float32): RN
    double yd0 = (double)yf0;

    // ENCODE
    double a0 = fabs(yd0);
    uint32_t yb0 = __float_as_uint(yf0);
    uint32_t Ef0 = (yb0 >> 23) & 0xFFu;
    uint32_t mbf0 = yb0 & 0x7FFFFFu;
    int e00 = (Ef0 == 0u) ? -126 : (int)Ef0 - 127;
    bool pw0 = ok0 && (a0 > 0.0) && (Ef0 != 0u) && (mbf0 == 0u);
    if (__builtin_expect(pw0, 0)) {  // exact pow2: ocml log boundary, verbatim
      double e0 = floor(log(a0) / LN2);
      e00 = (int)fmin(fmax(e0, -126.0), 127.0);
    }
    double p20 = P2t[e00 + 126];
    double m10 = a0 * p20;               // RN: may be W' +- eps
    double mant0 = (m10 - 1.0) * 8388608.0;  // Sterbenz-exact, exact scale
    int M0 = (int)rint(mant0);
    uint32_t mb0 = ((uint32_t)M0) & 0x7FFFFFu;
    int T0 = M0 ? __builtin_ctz((uint32_t)M0) : 23;
    int L0 = T0 < 22 ? T0 : 22;
    for (int sc = 0; sc <= L0; ++sc) {   // boundary scs: original f64 math
      double f = floor(mant0 * Lms[sc]);
      mb0 = (mb0 & ~(1u << sc)) | (((uint32_t)(((int)f) & 1)) << sc);
    }
    uint32_t ob0 = (yb0 & 0x80000000u) | etab[e00 + 127] | mb0;
    ob0 = (ok0 && a0 > 0.0) ? ob0 : 0u;

    // ---- store(cur): inverse bit movement + LUT expansion, NT -------------
    // nibble-reverse ob0 (slot k = position-k nibble), butterfly -> Z slot i
    // = this lane's (position kp) nibble of value i*8+g's word.
    uint32_t Z = nib_transpose8(nib_reverse(ob0), kp);
    const int cb = tile * 2048 + wid * 512 + lane;
#pragma unroll
    for (int i = 0; i < 8; ++i) {
      int g = cb + i * 64;
      if (g < n_chunks) {
        u32x4 o = lut16[(Z >> (4 * i)) & 0xFu];
        __builtin_nontemporal_store(o, &out[g]);
      }
    }

    if (!havenext) break;
    tile = ntile;
  }
}

extern "C" void kernel_launch(void* const* d_in, const int* in_sizes, int n_in,
                              void* d_out, int out_size, void* d_ws, size_t ws_size,
                              hipStream_t stream) {
  int n_vals = in_sizes[0] / 32;
  int n_tiles = (n_vals + 255) / 256;
  int grid = n_tiles < 1024 ? n_tiles : 1024;
  spike_gelu_kernel<<<grid, 256, 0, stream>>>(
      (const u32x4*)d_in[0], (u32x4*)d_out, n_vals, n_tiles);
}

// Round 13
// 414.511 us; speedup vs baseline: 1.0454x; 1.0116x over previous
//
#include <hip/hip_runtime.h>
#include <math.h>

// Full-fidelity emulation of the reference as run by jax-rocm EAGERLY on this
// GPU (x64 on): all f64 transcendentals are __ocml_*_f64 == this kernel's
// exp()/log(). Both stages are inexact because jax lowers exp2(z) ->
// exp(RN(z*RN(ln2))) -- reproduced bit-for-bit.
//
// R13 changes (numerics bit-identical; targets DRAM-demand duty cycle):
//  * Prefetch depth 2 via two register buffers with COMPILE-TIME roles
//    (loop unrolled x2: A-phase / B-phase bodies; no dynamic buffer index).
//    Invariant at phase top: cur buffer holds tile t (loaded 2 phases ago),
//    nxt holds t+1. Body: pack(cur) -> sched_barrier -> issue loads(t+2 ->
//    cur) -> f64 chain -> store(t). Loads are issued a FULL iteration ahead,
//    so every wave keeps 8KB in flight ~100% of the time (R8/R12 issued only
//    ~1 chain ahead: 0 bytes in flight for the back half of each iteration,
//    convoy-synchronized across the SIMD -> bursty DRAM demand, candidate
//    cause of the 68%-of-copy-BW plateau).
//    R5's dbuf regression mechanism (mid-chain pack + DS ops between sigmoid
//    and encode) is absent: pack stays at phase top, no mid-chain memory.
//  * VGPR: A[8]+B[8]=64 + chain ~45 + misc ~15 = ~124 < 128 cliff;
//    __launch_bounds__(256,4) caps at 128 (no spill expected, 4 waves/SIMD
//    preserved).
//  * Everything else R12 verbatim: persistent 1024x256 grid, per-block
//    tables, NT loads + NT stores (R9: removing NT = +15us), butterfly 8x8
//    nibble transpose pack/store (R12: proven correct, absmax==0), LDS LUT
//    expansion, no in-loop barriers.
//  * Encode shortcuts unchanged (absmax==0 eight rounds):
//    - mantissa!=0 -> floor(log(a)/LN2) == E exactly; subnormal -> clip ==
//      -126; mantissa==0 (exact pow2) -> rare verbatim ocml log() path.
//    - mant = M + e, |e| <~ 1e-8: for sc > ctz(M), floor(mant*Lm[sc]) ==
//      M>>sc exactly -> parity is bit sc of M; only sc <= ctz(M) (incl. the
//      pow2 M=0 "W-1 garbage" case) runs the original f64 mul+floor step.

#define LN2C 0x1.62e42fefa39efp-1  // RN(ln2), XLA's folded log(2)

typedef unsigned int u32x4 __attribute__((ext_vector_type(4)));

__device__ __forceinline__ uint32_t nib_transpose8(uint32_t x, int p) {
  // Transpose the 8x8 nibble matrix held across the 8 lanes of a group
  // (row = lane p, col = nibble slot k). Involution.
  uint32_t r;
  r = __shfl_xor(x, 1);
  x = (p & 1) ? ((x & 0xF0F0F0F0u) | ((r >> 4) & 0x0F0F0F0Fu))
              : ((x & 0x0F0F0F0Fu) | ((r << 4) & 0xF0F0F0F0u));
  r = __shfl_xor(x, 2);
  x = (p & 2) ? ((x & 0xFF00FF00u) | ((r >> 8) & 0x00FF00FFu))
              : ((x & 0x00FF00FFu) | ((r << 8) & 0xFF00FF00u));
  r = __shfl_xor(x, 4);
  x = (p & 4) ? ((x & 0xFFFF0000u) | ((r >> 16) & 0x0000FFFFu))
              : ((x & 0x0000FFFFu) | ((r << 16) & 0xFFFF0000u));
  return x;
}

__device__ __forceinline__ uint32_t nib_reverse(uint32_t x) {
  uint32_t b = __builtin_bswap32(x);
  return ((b >> 4) & 0x0F0F0F0Fu) | ((b << 4) & 0xF0F0F0F0u);
}

__device__ __forceinline__ void load_tile(const u32x4* __restrict__ in,
                                          int cb, int n_chunks,
                                          u32x4 (&B)[8]) {
#pragma unroll
  for (int i = 0; i < 8; ++i) {
    int g = cb + i * 64;
    u32x4 b = {0u, 0u, 0u, 0u};
    if (g < n_chunks) b = __builtin_nontemporal_load(&in[g]);
    B[i] = b;
  }
}

__device__ __forceinline__ uint32_t pack_tile(const u32x4 (&B)[8], int kp) {
  // Lane-local nibble accumulation + 8x8 butterfly + nibble-reverse ->
  // this lane's value word (v = vwave + kp*8 + (lane>>3)). See R10 proof.
  uint32_t X = 0u;
#pragma unroll
  for (int i = 0; i < 8; ++i) {
    u32x4 b = B[i];
    uint32_t nib = (((b.x >> 23) & 1u) << 3) | (((b.y >> 23) & 1u) << 2) |
                   (((b.z >> 23) & 1u) << 1) | ((b.w >> 23) & 1u);
    X |= nib << (4 * i);
  }
  return nib_reverse(nib_transpose8(X, kp));
}

__global__ __launch_bounds__(256, 4) void spike_gelu_kernel(
    const u32x4* __restrict__ in, u32x4* __restrict__ out,
    int n_vals, int n_tiles) {
#pragma clang fp contract(off)
  const double LN2 = LN2C;
  // Tables (exact ocml-call replicas of the reference's constant arrays):
  __shared__ double Wdec[8];     // decode exponent weights exp2emu(7..0)
  __shared__ double Lms[23];     // ladder scales exp2emu(0..-22)
  __shared__ double E1t[256];    // ordered Wdec sum -> exp((e_c-127)*LN2)
  __shared__ double Vdec[23];    // decode fraction weights exp2emu(-1..-23)
  __shared__ double P2t[254];    // encode exp(-e0*LN2), e0 in [-126,127]
  __shared__ uint32_t etab[256]; // 8-step exponent floor-ladder per eb
  __shared__ u32x4 lut16[16];    // nibble -> 4 pulse floats (x=bit3..w=bit0)

  const int tid = threadIdx.x;
  const int lane = tid & 63;
  const int kp = lane & 7;   // position within 8-lane group
  const int wid = tid >> 6;  // 0..3
  const int n_chunks = n_vals * 8;
  const int tstep = gridDim.x;  // grid-stride over 256-value tiles
  const int laneoff = wid * 512 + lane;

  int tile = blockIdx.x;

  // ---- prologue: tile-0 loads in flight under the table build -------------
  u32x4 A[8], Bb[8];
  load_tile(in, tile * 2048 + laneoff, n_chunks, A);

  // ---- table stage 1 ------------------------------------------------------
  if (tid < 8) Wdec[tid] = exp((double)(7 - tid) * LN2);
  if (tid >= 31 && tid < 54) Lms[tid - 31] = exp((double)(31 - tid) * LN2);
  __syncthreads();
  // ---- table stage 2 (reference op order) ---------------------------------
  if (tid == 0) {
    E1t[0] = exp(-126.0 * LN2);  // subnormal-branch scale (e_c==0)
  } else {
    double e_c = 0.0;
#pragma unroll
    for (int j = 0; j < 8; ++j)   // ascending-j einsum accumulation, verbatim
      if ((tid >> (7 - j)) & 1) e_c = e_c + Wdec[j];
    E1t[tid] = exp((e_c - 127.0) * LN2);
  }
  if (tid < 23) Vdec[tid] = exp((double)(-1 - tid) * LN2);
  if (tid < 254) P2t[tid] = exp((double)(126 - tid) * LN2);  // exp(-e0*LN2)
  if (tid < 16) {
    u32x4 e;
    e.x = ((tid >> 3) & 1u) * 0x3F800000u;
    e.y = ((tid >> 2) & 1u) * 0x3F800000u;
    e.z = ((tid >> 1) & 1u) * 0x3F800000u;
    e.w = (tid & 1u) * 0x3F800000u;
    lut16[tid] = e;
  }
  if (tid >= 1 && tid < 255) {  // exponent-bit ladder, original formula
    double eb = (double)tid;
    uint32_t r = 0;
#pragma unroll
    for (int sc = 7; sc >= 0; --sc) {
      double f = floor(eb * Lms[sc]);
      double md = f - 2.0 * floor(0.5 * f);
      r |= ((uint32_t)md) << (23 + sc);
    }
    etab[tid] = r;
  } else if (tid == 255 || tid == 0) {
    etab[tid] = 0u;  // hygiene, never read
  }
  __syncthreads();  // tables ready; no further block-wide coupling

  // ---- prologue: tile-1 loads (prefetch depth 2 established) --------------
  if (tile + tstep < n_tiles)
    load_tile(in, (tile + tstep) * 2048 + laneoff, n_chunks, Bb);

  // chain + store, factored (compile-time everything; see R10 proof for the
  // store-side inverse butterfly + LUT expansion)
  auto chain_store = [&](uint32_t w0, int t) {
    const int vwave = t * 256 + wid * 64;
    const int v0 = vwave + kp * 8 + (lane >> 3);
    const bool ok0 = v0 < n_vals;

    // DECODE
    double f0 = 0.0;
#pragma unroll
    for (int j = 0; j < 23; ++j)
      if ((w0 >> (22 - j)) & 1u) f0 = f0 + Vdec[j];
    uint32_t ei0 = (w0 >> 23) & 0xFFu;
    double sg0 = (w0 >> 31) ? -1.0 : 1.0;
    double fa0 = ei0 ? (1.0 + f0) : f0;
    double x0 = (sg0 * E1t[ei0]) * fa0;

    // f64 GELU, exp-form logistic, ocml exp
    double t0 = 1.702 * x0;
    double e0v = exp(-t0);
    double s0 = 1.0 / (1.0 + e0v);
    double y0 = x0 * s0;
    float yf0 = (float)y0;   // astype(float32): RN
    double yd0 = (double)yf0;

    // ENCODE
    double a0 = fabs(yd0);
    uint32_t yb0 = __float_as_uint(yf0);
    uint32_t Ef0 = (yb0 >> 23) & 0xFFu;
    uint32_t mbf0 = yb0 & 0x7FFFFFu;
    int e00 = (Ef0 == 0u) ? -126 : (int)Ef0 - 127;
    bool pw0 = ok0 && (a0 > 0.0) && (Ef0 != 0u) && (mbf0 == 0u);
    if (__builtin_expect(pw0, 0)) {  // exact pow2: ocml log boundary
      double e0 = floor(log(a0) / LN2);
      e00 = (int)fmin(fmax(e0, -126.0), 127.0);
    }
    double p20 = P2t[e00 + 126];
    double m10 = a0 * p20;               // RN: may be W' +- eps
    double mant0 = (m10 - 1.0) * 8388608.0;  // Sterbenz-exact, exact scale
    int M0 = (int)rint(mant0);
    uint32_t mb0 = ((uint32_t)M0) & 0x7FFFFFu;
    int T0 = M0 ? __builtin_ctz((uint32_t)M0) : 23;
    int L0 = T0 < 22 ? T0 : 22;
    for (int sc = 0; sc <= L0; ++sc) {   // boundary scs: original f64 math
      double f = floor(mant0 * Lms[sc]);
      mb0 = (mb0 & ~(1u << sc)) | (((uint32_t)(((int)f) & 1)) << sc);
    }
    uint32_t ob0 = (yb0 & 0x80000000u) | etab[e00 + 127] | mb0;
    ob0 = (ok0 && a0 > 0.0) ? ob0 : 0u;

    // store: inverse butterfly + LUT expansion, NT
    uint32_t Z = nib_transpose8(nib_reverse(ob0), kp);
    const int cb = t * 2048 + laneoff;
#pragma unroll
    for (int i = 0; i < 8; ++i) {
      int g = cb + i * 64;
      if (g < n_chunks) {
        u32x4 o = lut16[(Z >> (4 * i)) & 0xFu];
        __builtin_nontemporal_store(o, &out[g]);
      }
    }
  };

  // ---- steady-state: unrolled x2 (A-phase / B-phase), depth-2 prefetch ----
  for (;;) {
    // A-phase: cur=A holds tile; B holds tile+tstep (in flight or arrived)
    {
      uint32_t w0 = pack_tile(A, kp);          // waits only A's (oldest) loads
      __builtin_amdgcn_sched_barrier(0);       // don't hoist refill above pack
      int t2 = tile + 2 * tstep;
      if (t2 < n_tiles) load_tile(in, t2 * 2048 + laneoff, n_chunks, A);
      chain_store(w0, tile);
    }
    if (tile + tstep >= n_tiles) break;

    // B-phase: cur=B holds tile+tstep; A holds tile+2*tstep (in flight)
    {
      int tb = tile + tstep;
      uint32_t w0 = pack_tile(Bb, kp);
      __builtin_amdgcn_sched_barrier(0);
      int t3 = tb + 2 * tstep;
      if (t3 < n_tiles) load_tile(in, t3 * 2048 + laneoff, n_chunks, Bb);
      chain_store(w0, tb);
    }
    tile += 2 * tstep;
    if (tile >= n_tiles) break;
  }
}

extern "C" void kernel_launch(void* const* d_in, const int* in_sizes, int n_in,
                              void* d_out, int out_size, void* d_ws, size_t ws_size,
                              hipStream_t stream) {
  int n_vals = in_sizes[0] / 32;
  int n_tiles = (n_vals + 255) / 256;
  int grid = n_tiles < 1024 ? n_tiles : 1024;
  spike_gelu_kernel<<<grid, 256, 0, stream>>>(
      (const u32x4*)d_in[0], (u32x4*)d_out, n_vals, n_tiles);
}